// Round 6
// baseline (55.566 us; speedup 1.0000x reference)
//
#include <hip/hip_runtime.h>
#include <hip/hip_bf16.h>

// ClassBalancedSupConLoss, B=8192, D=128.
// loss_i = -(BASE/t_i)*[P_i - C_i*lse_i]/(C_i+eps)
//   P_i   = invt_i*(e_i.S_{c(i)} - ||e_i||^2)      (fp32 closed form)
//   C_i   = count_{c(i)} - 1
//   lse_i = invt_i*||e_i||^2 + ln(Z_i),  Z_i = sum_j exp2(v_ij - m_i),
//           m_i = invt_i*log2e*||e_i||^2 (fixed reference; exact for any m)
// k2: 32x32x16 bf16 MFMA, swapped operands; single accumulator chain
// initialized to -m so exp2 args come straight off the matrix pipe.
// Ebf in MFMA-fragment-tiled order (validated r4):
//   (r,k) -> tile r>>5, chunk k>>4, lane (r&31)+((k>>3)&1)*32, e k&7.
// All cross-block reductions: fixed-point int64 atomics (deterministic);
// final scalar via last-block ticket (no separate kernel, no memset node).

#define B_ROWS 8192
#define D_DIM 128
#define BASE_TEMP 0.07f
#define LOG2E 1.4426950408889634f
#define LN2 0.6931471805599453f
#define FIX_SCALE 1048576.0f   // 2^20

typedef __bf16 bf16x8 __attribute__((ext_vector_type(8)));
typedef __bf16 bf16x4 __attribute__((ext_vector_type(4)));
typedef float floatx16 __attribute__((ext_vector_type(16)));
typedef unsigned long long u64;

__device__ __forceinline__ float class_invtemp(int lbl) {
    return (lbl == 0) ? 12.5f : ((lbl == 1) ? 20.0f : 10.0f);
}

__device__ __forceinline__ u64 fix64(float v) {
    return (u64)(long long)llrintf(v * FIX_SCALE);
}

// ---- KZ: zero the 4 KB atomic-accumulator region (replaces memset node) ----
__global__ __launch_bounds__(256) void kz_zero(u64* __restrict__ a) {
    a[threadIdx.x] = 0ull;
    a[256 + threadIdx.x] = 0ull;
}

// ---- K0: cast->tiled bf16 + row norms (fused pass), class sums/counts ----
__global__ __launch_bounds__(256) void k0_prep(
        const float* __restrict__ E, const int* __restrict__ labels,
        __bf16* __restrict__ Ebf, float* __restrict__ nrm,
        u64* __restrict__ Sfix /*[3*128]*/, u64* __restrict__ cntfix /*[3]*/) {
    const int blk = blockIdx.x;          // 256 blocks x 32 rows
    const int tid = threadIdx.x;
    const int row0 = blk * 32;

    __shared__ float sh[3][128];
    __shared__ int scnt[3];
    if (tid < 3) scnt[tid] = 0;

    // pass 1: cast to tiled fragment layout + row norms (32 lanes per row)
    const float4* src = reinterpret_cast<const float4*>(E + (size_t)row0 * D_DIM);
    #pragma unroll
    for (int p = 0; p < 4; ++p) {
        int idx = p * 256 + tid;         // 1024 float4 = 32 rows x 32 k4
        float4 v = src[idx];
        int r = idx >> 5, k4 = idx & 31;
        int R = row0 + r;
        int T = R >> 5;
        int l = (R & 31) + ((k4 >> 1) & 1) * 32;
        int c = k4 >> 2;
        size_t dst = (size_t)T * 4096 + c * 512 + l * 8 + (k4 & 1) * 4;
        bf16x4 o = { (__bf16)v.x, (__bf16)v.y, (__bf16)v.z, (__bf16)v.w };
        *reinterpret_cast<bf16x4*>(Ebf + dst) = o;
        // norm: 32 consecutive lanes hold one full row
        float s = v.x * v.x + v.y * v.y + v.z * v.z + v.w * v.w;
        s += __shfl_xor(s, 1);  s += __shfl_xor(s, 2);  s += __shfl_xor(s, 4);
        s += __shfl_xor(s, 8);  s += __shfl_xor(s, 16);
        if ((tid & 31) == 0) nrm[R] = s;
    }

    // pass 2: class sums (L1/L2-hot), fixed-point atomics
    const int d = tid & 127, half = tid >> 7;
    float s0 = 0.f, s1 = 0.f, s2 = 0.f;
    #pragma unroll 4
    for (int r2 = 0; r2 < 16; ++r2) {
        int r = row0 + half * 16 + r2;
        float v = E[(size_t)r * D_DIM + d];
        int l = labels[r];
        s0 += (l == 0) ? v : 0.f;
        s1 += (l == 1) ? v : 0.f;
        s2 += (l == 2) ? v : 0.f;
    }
    if (half == 1) { sh[0][d] = s0; sh[1][d] = s1; sh[2][d] = s2; }
    __syncthreads();
    if (half == 0) {
        atomicAdd(&Sfix[d],       fix64(s0 + sh[0][d]));
        atomicAdd(&Sfix[128 + d], fix64(s1 + sh[1][d]));
        atomicAdd(&Sfix[256 + d], fix64(s2 + sh[2][d]));
    }
    if (tid < 32) atomicAdd(&scnt[labels[row0 + tid]], 1);
    __syncthreads();
    if (tid < 3) atomicAdd(&cntfix[tid], (u64)scnt[tid]);
}

// ---- K2: fixed-m softmax denominators; part[split][i] = Z partial ----
__global__ __launch_bounds__(256, 3) void k2_stats(
        const __bf16* __restrict__ Ebf, const int* __restrict__ labels,
        const float* __restrict__ nrm, float* __restrict__ part,
        int nsplit, int jrange) {
    const int lane = threadIdx.x & 63;
    const int wave = threadIdx.x >> 6;
    const int split = blockIdx.y;
    const int j0 = split * jrange;
    const int col = lane & 31;
    const int icol = blockIdx.x * 128 + wave * 32 + col;

    const float bscale = class_invtemp(labels[icol]) * LOG2E;
    const float negm = -bscale * nrm[icol];   // -(log2-domain self logit)

    // B frag (i side), pre-scaled, tiled layout
    const int iT = blockIdx.x * 4 + wave;
    const __bf16* bbase = Ebf + (size_t)iT * 4096 + lane * 8;
    bf16x8 Bf[8];
    #pragma unroll
    for (int c = 0; c < 8; ++c) {
        bf16x8 raw = *reinterpret_cast<const bf16x8*>(bbase + c * 512);
        bf16x8 sc;
        #pragma unroll
        for (int e = 0; e < 8; ++e) sc[e] = (__bf16)((float)raw[e] * bscale);
        Bf[c] = sc;
    }

    const __bf16* abase = Ebf + ((size_t)(j0 >> 5)) * 4096 + lane * 8;
    bf16x8 A0[8], A1[8];
    #pragma unroll
    for (int c = 0; c < 8; ++c)
        A0[c] = *reinterpret_cast<const bf16x8*>(abase + c * 512);

    float Zacc[16];
    #pragma unroll
    for (int r = 0; r < 16; ++r) Zacc[r] = 0.f;
    const int nsteps = jrange >> 5;

    auto k2_step = [&](const bf16x8* Ab) {
        floatx16 acc;
        #pragma unroll
        for (int r = 0; r < 16; ++r) acc[r] = negm;
        #pragma unroll
        for (int c = 0; c < 8; ++c)
            acc = __builtin_amdgcn_mfma_f32_32x32x16_bf16(Ab[c], Bf[c], acc, 0, 0, 0);
        #pragma unroll
        for (int r = 0; r < 16; ++r)
            Zacc[r] += __builtin_amdgcn_exp2f(acc[r]);
    };

    for (int s = 0; s < nsteps; s += 2) {
        {   // consume A0 (step s), prefetch s+1 -> A1
            const __bf16* ap = abase + (size_t)(s + 1) * 4096;
            #pragma unroll
            for (int c = 0; c < 8; ++c)
                A1[c] = *reinterpret_cast<const bf16x8*>(ap + c * 512);
            k2_step(A0);
        }
        {   // consume A1 (step s+1), prefetch s+2 -> A0
            if (s + 2 < nsteps) {
                const __bf16* ap = abase + (size_t)(s + 2) * 4096;
                #pragma unroll
                for (int c = 0; c < 8; ++c)
                    A0[c] = *reinterpret_cast<const bf16x8*>(ap + c * 512);
            }
            k2_step(A1);
        }
    }

    float t0 = (Zacc[0] + Zacc[1]) + (Zacc[2] + Zacc[3]);
    float t1 = (Zacc[4] + Zacc[5]) + (Zacc[6] + Zacc[7]);
    float t2 = (Zacc[8] + Zacc[9]) + (Zacc[10] + Zacc[11]);
    float t3 = (Zacc[12] + Zacc[13]) + (Zacc[14] + Zacc[15]);
    float Zt = (t0 + t1) + (t2 + t3);
    Zt += __shfl_xor(Zt, 32);     // lanes l, l+32 hold same i-col
    if (lane < 32)
        part[(size_t)split * B_ROWS + icol] = Zt;
}

// ---- K3: per-row loss (8 thr/row), fixed-point accumulate + ticket finish ----
__global__ __launch_bounds__(256) void k3_rowloss(
        const float* __restrict__ E, const int* __restrict__ labels,
        const u64* __restrict__ Sfix, const u64* __restrict__ cntfix,
        const float* __restrict__ nrm, const float* __restrict__ part,
        int nsplit, u64* __restrict__ lossfix, u64* __restrict__ validfix,
        unsigned int* __restrict__ done, float* __restrict__ out) {
    __shared__ float sS[384];
    const int tid = threadIdx.x;
    if (tid < 128) {
        sS[tid]       = (float)(long long)Sfix[tid]       * (1.0f / FIX_SCALE);
        sS[128 + tid] = (float)(long long)Sfix[128 + tid] * (1.0f / FIX_SCALE);
        sS[256 + tid] = (float)(long long)Sfix[256 + tid] * (1.0f / FIX_SCALE);
    }
    __syncthreads();

    const int r = tid >> 3, g = tid & 7;          // 32 rows/block, 8 thr/row
    const int i = blockIdx.x * 32 + r;
    const int lab = labels[i];
    const float invt = class_invtemp(lab);

    const float4* er = reinterpret_cast<const float4*>(E + (size_t)i * D_DIM);
    const float4* sr = reinterpret_cast<const float4*>(&sS[lab * 128]);
    float dotS = 0.f;
    #pragma unroll
    for (int q = 0; q < 4; ++q) {
        float4 v = er[g * 4 + q];
        float4 s = sr[g * 4 + q];
        dotS += v.x * s.x + v.y * s.y + v.z * s.z + v.w * s.w;
    }
    float Zp = 0.f;
    for (int p = g; p < nsplit; p += 8)
        Zp += part[(size_t)p * B_ROWS + i];

    // butterfly over the 8-thread group (all lanes get totals)
    #pragma unroll
    for (int off = 1; off < 8; off <<= 1) {
        dotS += __shfl_xor(dotS, off);
        Zp   += __shfl_xor(Zp, off);
    }

    float loss = 0.f;
    int valid = 0;
    if (g == 0) {
        const float nr = nrm[i];
        const float C = (float)(long long)cntfix[lab] - 1.0f;
        // lse_nat = m*ln2 + ln(Z), m = invt*log2e*nr -> m*ln2 = invt*nr
        const float lse = invt * nr + LN2 * __builtin_amdgcn_logf(Zp);
        const float P_nat = invt * (dotS - nr);
        if (C > 0.f) {
            loss = -(BASE_TEMP * invt) * (P_nat - C * lse) / (C + 1e-8f);
            valid = 1;
        }
    }
    // sum the 8 per-row lanes (0,8,...,56) within each wave
    loss  += __shfl_down(loss, 8);   valid += __shfl_down(valid, 8);
    loss  += __shfl_down(loss, 16);  valid += __shfl_down(valid, 16);
    loss  += __shfl_down(loss, 32);  valid += __shfl_down(valid, 32);

    __shared__ float rl[4];
    __shared__ int rv[4];
    if ((tid & 63) == 0) { rl[tid >> 6] = loss; rv[tid >> 6] = valid; }
    __syncthreads();
    if (tid == 0) {
        float bt = (rl[0] + rl[1]) + (rl[2] + rl[3]);
        int bv = (rv[0] + rv[1]) + (rv[2] + rv[3]);
        atomicAdd(lossfix, fix64(bt));
        atomicAdd(validfix, (u64)bv);
        __threadfence();
        unsigned int t = atomicAdd(done, 1u);
        if (t == gridDim.x - 1) {   // last block: finalize (deterministic value)
            u64 L = atomicAdd(lossfix, 0ull);
            u64 V = atomicAdd(validfix, 0ull);
            double T = (double)(long long)L * (1.0 / (double)FIX_SCALE);
            double N = (double)(long long)V;
            out[0] = (N > 0.0) ? (float)(T / fmax(N, 1.0)) : 0.f;
        }
    }
}

extern "C" void kernel_launch(void* const* d_in, const int* in_sizes, int n_in,
                              void* d_out, int out_size, void* d_ws, size_t ws_size,
                              hipStream_t stream) {
    const float* E = (const float*)d_in[0];
    const int* labels = (const int*)d_in[1];
    float* out = (float*)d_out;
    char* ws = (char*)d_ws;

    // workspace layout
    const size_t OFF_EBF = 0;                         // 2 MB tiled bf16
    const size_t OFF_ATOM = (size_t)2 << 20;          // 4 KB accumulators
    const size_t OFF_NRM = OFF_ATOM + 4096;           // 32 KB row norms
    const size_t OFF_PART = OFF_NRM + (size_t)B_ROWS * 4;  // part[split][B]

    int nsplit = 8;
    if (ws_size >= OFF_PART + (size_t)32 * B_ROWS * 4) nsplit = 32;
    else if (ws_size >= OFF_PART + (size_t)16 * B_ROWS * 4) nsplit = 16;
    const int jrange = B_ROWS / nsplit;

    __bf16* Ebf = (__bf16*)(ws + OFF_EBF);
    u64* Sfix = (u64*)(ws + OFF_ATOM);                // [0..383]
    u64* cntfix = Sfix + 384;                         // [384..386]
    u64* lossfix = Sfix + 388;
    u64* validfix = Sfix + 389;
    unsigned int* done = (unsigned int*)(Sfix + 390);
    float* nrm = (float*)(ws + OFF_NRM);
    float* part = (float*)(ws + OFF_PART);

    kz_zero<<<1, 256, 0, stream>>>(Sfix);
    k0_prep<<<256, 256, 0, stream>>>(E, labels, Ebf, nrm, Sfix, cntfix);
    k2_stats<<<dim3(64, nsplit), 256, 0, stream>>>(Ebf, labels, nrm, part, nsplit, jrange);
    k3_rowloss<<<256, 256, 0, stream>>>(E, labels, Sfix, cntfix, nrm, part,
                                        nsplit, lossfix, validfix, done, out);
}